// Round 3
// baseline (1209.104 us; speedup 1.0000x reference)
//
#include <hip/hip_runtime.h>
#include <hip/hip_cooperative_groups.h>
#include <math.h>

namespace cg = cooperative_groups;

#define EPS 1e-5f
#define INV_N (1.0f / 1024.0f)

// out layout: prob[1024] @0, o1[1024*300] @1024, o2 @308224
// Single cooperative kernel, grid 256 x 256 threads, 8 grid.sync()s.
// All GEMMs: fp16-input MFMA (fp32 accumulate), K/N zero-padded.

typedef _Float16 f16x8 __attribute__((ext_vector_type(8)));
typedef float f32x4 __attribute__((ext_vector_type(4)));

__device__ __forceinline__ _Float16 f2h(float f) { return (_Float16)f; }

struct Params {
    const int *langs1, *sents1, *langs2, *sents2;
    const float *tables, *w1, *b1, *w2, *b2, *w3, *b3, *w4, *b4, *w5, *b5;
    float *F0, *F1, *stats, *out;
    _Float16 *xb, *a1b, *nxtb, *a3b, *w1b, *w2b, *w3b, *w4b;
};

// ---------------------------------------------------------------------------
// MFMA GEMM tile (validated in R2): C[64x64 tile] = A @ W^T + bias, fp32 out.
// 256 thr = 4 waves (2x2), each wave 32x32 via 2x2 16x16x32 f16 frags.
// Column sums/sumsqs atomically accumulated (side 1 for rows>=1024 if 2-sided).
// ---------------------------------------------------------------------------
__device__ void gemm_tile(const _Float16* __restrict__ A,
                          const _Float16* __restrict__ W, int ldk,
                          const float* __restrict__ bias,
                          float* __restrict__ C, int ldc, int N, int kIters,
                          float* __restrict__ sSum, float* __restrict__ sSq,
                          int twoSided, int bx, int by,
                          _Float16* lsA, _Float16* lsW)
{
    int tid = threadIdx.x;
    int r0 = bx * 64, c0 = by * 64;
    int lane = tid & 63;
    int wave = tid >> 6;
    int waveR = wave & 1, waveC = wave >> 1;
    int q = lane >> 4, m = lane & 15;

    int srow = tid >> 2, sseg = tid & 3;
    const _Float16* gA = A + (size_t)(r0 + srow) * ldk + sseg * 8;
    const _Float16* gW = W + (size_t)(c0 + srow) * ldk + sseg * 8;
    _Float16* stA = &lsA[sseg * 512 + srow * 8];
    _Float16* stW = &lsW[sseg * 512 + srow * 8];

    int aoff0 = q * 512 + (waveR * 32 + m) * 8;
    int aoff1 = aoff0 + 128;
    int boff0 = q * 512 + (waveC * 32 + m) * 8;
    int boff1 = boff0 + 128;

    f32x4 acc00 = {0.f,0.f,0.f,0.f}, acc01 = {0.f,0.f,0.f,0.f};
    f32x4 acc10 = {0.f,0.f,0.f,0.f}, acc11 = {0.f,0.f,0.f,0.f};

    for (int kt = 0; kt < kIters; kt++) {
        uint4 va = *(const uint4*)gA;
        uint4 vw = *(const uint4*)gW;
        gA += 32; gW += 32;
        __syncthreads();
        *(uint4*)stA = va;
        *(uint4*)stW = vw;
        __syncthreads();
        f16x8 a0 = *(const f16x8*)&lsA[aoff0];
        f16x8 a1 = *(const f16x8*)&lsA[aoff1];
        f16x8 b0 = *(const f16x8*)&lsW[boff0];
        f16x8 b1 = *(const f16x8*)&lsW[boff1];
        acc00 = __builtin_amdgcn_mfma_f32_16x16x32_f16(a0, b0, acc00, 0, 0, 0);
        acc01 = __builtin_amdgcn_mfma_f32_16x16x32_f16(a0, b1, acc01, 0, 0, 0);
        acc10 = __builtin_amdgcn_mfma_f32_16x16x32_f16(a1, b0, acc10, 0, 0, 0);
        acc11 = __builtin_amdgcn_mfma_f32_16x16x32_f16(a1, b1, acc11, 0, 0, 0);
    }

    int side = (twoSided && r0 >= 1024) ? 1 : 0;
    int gc0 = c0 + waveC * 32 + m;
    int gc1 = gc0 + 16;
    float bias0 = (gc0 < N) ? bias[gc0] : 0.f;
    float bias1 = (gc1 < N) ? bias[gc1] : 0.f;
    float colS0 = 0.f, colQ0 = 0.f, colS1 = 0.f, colQ1 = 0.f;
    #pragma unroll
    for (int i = 0; i < 2; i++) {
        f32x4 cv0 = i ? acc10 : acc00;
        f32x4 cv1 = i ? acc11 : acc01;
        #pragma unroll
        for (int r = 0; r < 4; r++) {
            int gr = r0 + waveR * 32 + i * 16 + q * 4 + r;
            if (gc0 < N) {
                float v = cv0[r] + bias0;
                C[(size_t)gr * ldc + gc0] = v;
                colS0 += v; colQ0 += v * v;
            }
            if (gc1 < N) {
                float v = cv1[r] + bias1;
                C[(size_t)gr * ldc + gc1] = v;
                colS1 += v; colQ1 += v * v;
            }
        }
    }
    colS0 += __shfl_down(colS0, 32); colS0 += __shfl_down(colS0, 16);
    colQ0 += __shfl_down(colQ0, 32); colQ0 += __shfl_down(colQ0, 16);
    colS1 += __shfl_down(colS1, 32); colS1 += __shfl_down(colS1, 16);
    colQ1 += __shfl_down(colQ1, 32); colQ1 += __shfl_down(colQ1, 16);
    if (q == 0) {
        if (gc0 < N) {
            atomicAdd(&sSum[side * N + gc0], colS0);
            atomicAdd(&sSq[side * N + gc0], colQ0);
        }
        if (gc1 < N) {
            atomicAdd(&sSum[side * N + gc1], colS1);
            atomicAdd(&sSq[side * N + gc1], colQ1);
        }
    }
}

// ---------------------------------------------------------------------------
__global__ __launch_bounds__(256) void fused_kernel(Params p)
{
    cg::grid_group grid = cg::this_grid();
    __shared__ __align__(16) _Float16 lsA[2048];
    __shared__ __align__(16) _Float16 lsW[2048];
    __shared__ float redbuf[8];
    __shared__ int toks[50];

    const int t = threadIdx.x;
    const int lane = t & 63, wave = t >> 6;
    const int bid = blockIdx.x;
    const int gsz = gridDim.x * 256;   // 65536

    float* s1S = p.stats;        float* s1Q = p.stats + 600;
    float* s2S = p.stats + 1200; float* s2Q = p.stats + 1800;
    float* s3S = p.stats + 2400; float* s3Q = p.stats + 2800;
    float* s4S = p.stats + 3200; float* s4Q = p.stats + 3300;

    // ---- S0: zero stats + gather -> xb (f16, 300->320 pad) + weight cvt ----
    { int i = bid * 256 + t; if (i < 3400) p.stats[i] = 0.f; }

    for (int v = bid; v < 2048; v += gridDim.x) {
        int side = v >> 10, b = v & 1023;
        const int* langs = side ? p.langs2 : p.langs1;
        const int* sents = side ? p.sents2 : p.sents1;
        __syncthreads();
        if (t < 50) toks[t] = sents[b * 50 + t];
        __syncthreads();
        const float* base = p.tables + (size_t)langs[b] * (200000ull * 300ull);
        float a0 = 0.f, a1 = 0.f;
        #pragma unroll 5
        for (int s = 0; s < 50; s++) {
            const float* row = base + (size_t)toks[s] * 300;
            a0 += row[t];
            if (t < 44) a1 += row[t + 256];
        }
        _Float16* xr = p.xb + (size_t)v * 320;
        xr[t] = f2h(a0);
        if (t < 64) xr[t + 256] = (t < 44) ? f2h(a1) : (_Float16)0.f;
    }

    for (int i = bid * 256 + t; i < 673792; i += gsz) {
        if (i < 102400) {
            int r = i / 320, c = i - r * 320;
            p.w1b[i] = (r < 300 && c < 300) ? f2h(p.w1[r * 300 + c]) : (_Float16)0.f;
        } else if (i < 204800) {
            int j = i - 102400; int r = j / 320, c = j - r * 320;
            p.w2b[j] = (r < 300 && c < 300) ? f2h(p.w2[r * 300 + c]) : (_Float16)0.f;
        } else if (i < 620544) {
            int j = i - 204800; int r = j / 928, c = j - r * 928;
            p.w3b[j] = (r < 400 && c < 901) ? f2h(p.w3[r * 901 + c]) : (_Float16)0.f;
        } else {
            int j = i - 620544; int r = j / 416, c = j - r * 416;
            p.w4b[j] = (r < 100 && c < 400) ? f2h(p.w4[r * 400 + c]) : (_Float16)0.f;
        }
    }
    __threadfence();
    grid.sync();

    // ---- S1: z1 = x @ w1^T + b1 -> F0; stats1 (160 tiles) ----
    if (bid < 160)
        gemm_tile(p.xb, p.w1b, 320, p.b1, p.F0, 300, 300, 10,
                  s1S, s1Q, 1, bid & 31, bid >> 5, lsA, lsW);
    __threadfence();
    grid.sync();

    // ---- S2: a1 = f16(relu(bn1(z1))) -> a1b ----
    for (int i = bid * 256 + t; i < 655360; i += gsz) {
        int r = i / 320, c = i - r * 320;
        _Float16 v = (_Float16)0.f;
        if (c < 300) {
            int side = r >> 10;
            float mean = s1S[side * 300 + c] * INV_N;
            float var  = s1Q[side * 300 + c] * INV_N - mean * mean;
            float x = (p.F0[r * 300 + c] - mean) * rsqrtf(var + EPS);
            v = f2h(fmaxf(x, 0.f));
        }
        p.a1b[i] = v;
    }
    __threadfence();
    grid.sync();

    // ---- S3: z2 = a1 @ w2^T + b2 -> F1; stats2 (160 tiles) ----
    if (bid < 160)
        gemm_tile(p.a1b, p.w2b, 320, p.b2, p.F1, 300, 300, 10,
                  s2S, s2Q, 1, bid & 31, bid >> 5, lsA, lsW);
    __threadfence();
    grid.sync();

    // ---- S4: o1,o2 -> out (fp32); nxt -> nxtb (f16, 901->928 pad) ----
    for (int v = bid; v < 1024; v += gridDim.x) {
        float dot = 0.f;
        {
            int d = t;   // 0..255 < 300
            float m1 = s2S[d] * INV_N;
            float v1 = s2Q[d] * INV_N - m1 * m1;
            float m2 = s2S[300 + d] * INV_N;
            float v2 = s2Q[300 + d] * INV_N - m2 * m2;
            float a1 = fmaxf((p.F1[(size_t)v * 300 + d] - m1) * rsqrtf(v1 + EPS), 0.f);
            float a2 = fmaxf((p.F1[(size_t)(1024 + v) * 300 + d] - m2) * rsqrtf(v2 + EPS), 0.f);
            p.out[1024 + (size_t)v * 300 + d] = a1;
            p.out[308224 + (size_t)v * 300 + d] = a2;
            p.nxtb[(size_t)v * 928 + d] = f2h(a1);
            p.nxtb[(size_t)v * 928 + 300 + d] = f2h(a2);
            p.nxtb[(size_t)v * 928 + 600 + d] = f2h(fabsf(a1 - a2));
            dot += a1 * a2;
        }
        if (t < 44) {
            int d = t + 256;
            float m1 = s2S[d] * INV_N;
            float v1 = s2Q[d] * INV_N - m1 * m1;
            float m2 = s2S[300 + d] * INV_N;
            float v2 = s2Q[300 + d] * INV_N - m2 * m2;
            float a1 = fmaxf((p.F1[(size_t)v * 300 + d] - m1) * rsqrtf(v1 + EPS), 0.f);
            float a2 = fmaxf((p.F1[(size_t)(1024 + v) * 300 + d] - m2) * rsqrtf(v2 + EPS), 0.f);
            p.out[1024 + (size_t)v * 300 + d] = a1;
            p.out[308224 + (size_t)v * 300 + d] = a2;
            p.nxtb[(size_t)v * 928 + d] = f2h(a1);
            p.nxtb[(size_t)v * 928 + 300 + d] = f2h(a2);
            p.nxtb[(size_t)v * 928 + 600 + d] = f2h(fabsf(a1 - a2));
            dot += a1 * a2;
        }
        #pragma unroll
        for (int off = 32; off; off >>= 1) dot += __shfl_down(dot, off);
        __syncthreads();
        if (lane == 0) redbuf[wave] = dot;
        __syncthreads();
        if (t == 0)
            p.nxtb[(size_t)v * 928 + 900] =
                f2h(redbuf[0] + redbuf[1] + redbuf[2] + redbuf[3]);
        if (t < 27) p.nxtb[(size_t)v * 928 + 901 + t] = (_Float16)0.f;
    }
    __threadfence();
    grid.sync();

    // ---- S5: y3 = nxt @ w3^T + b3 -> F0; stats3 (112 tiles) ----
    if (bid < 112)
        gemm_tile(p.nxtb, p.w3b, 928, p.b3, p.F0, 400, 400, 29,
                  s3S, s3Q, 0, bid & 15, bid >> 4, lsA, lsW);
    __threadfence();
    grid.sync();

    // ---- S6: a3 = f16(relu(bn3(y3))) -> a3b ----
    for (int i = bid * 256 + t; i < 425984; i += gsz) {
        int r = i / 416, c = i - r * 416;
        _Float16 v = (_Float16)0.f;
        if (c < 400) {
            float mean = s3S[c] * INV_N;
            float var  = s3Q[c] * INV_N - mean * mean;
            float x = (p.F0[r * 400 + c] - mean) * rsqrtf(var + EPS);
            v = f2h(fmaxf(x, 0.f));
        }
        p.a3b[i] = v;
    }
    __threadfence();
    grid.sync();

    // ---- S7: y4 = a3 @ w4^T + b4 -> F1; stats4 (32 tiles) ----
    if (bid < 32)
        gemm_tile(p.a3b, p.w4b, 416, p.b4, p.F1, 100, 100, 13,
                  s4S, s4Q, 0, bid & 15, bid >> 4, lsA, lsW);
    __threadfence();
    grid.sync();

    // ---- S8: prob = sigmoid(bn4+relu . w5 + b5) -> out[0:1024] ----
    {
        int r = bid * 4 + wave;   // exactly 1024 rows
        float acc = 0.f;
        {
            int j = lane;   // < 64 < 100
            float mean = s4S[j] * INV_N;
            float var  = s4Q[j] * INV_N - mean * mean;
            float v = (p.F1[(size_t)r * 100 + j] - mean) * rsqrtf(var + EPS);
            acc += fmaxf(v, 0.f) * p.w5[j];
        }
        if (lane < 36) {
            int j = lane + 64;
            float mean = s4S[j] * INV_N;
            float var  = s4Q[j] * INV_N - mean * mean;
            float v = (p.F1[(size_t)r * 100 + j] - mean) * rsqrtf(var + EPS);
            acc += fmaxf(v, 0.f) * p.w5[j];
        }
        #pragma unroll
        for (int off = 32; off; off >>= 1) acc += __shfl_down(acc, off);
        if (lane == 0) p.out[r] = 1.f / (1.f + expf(-(acc + p.b5[0])));
    }
}

// ---------------------------------------------------------------------------
extern "C" void kernel_launch(void* const* d_in, const int* in_sizes, int n_in,
                              void* d_out, int out_size, void* d_ws, size_t ws_size,
                              hipStream_t stream)
{
    float* ws = (float*)d_ws;
    _Float16* hb = (_Float16*)(ws + 1232208);

    Params p;
    p.langs1 = (const int*)d_in[0];
    p.sents1 = (const int*)d_in[1];
    p.langs2 = (const int*)d_in[2];
    p.sents2 = (const int*)d_in[3];
    p.tables = (const float*)d_in[4];
    p.w1 = (const float*)d_in[5];  p.b1 = (const float*)d_in[6];
    p.w2 = (const float*)d_in[7];  p.b2 = (const float*)d_in[8];
    p.w3 = (const float*)d_in[9];  p.b3 = (const float*)d_in[10];
    p.w4 = (const float*)d_in[11]; p.b4 = (const float*)d_in[12];
    p.w5 = (const float*)d_in[13]; p.b5 = (const float*)d_in[14];
    p.F0 = ws;
    p.F1 = ws + 614400;
    p.stats = ws + 1228800;
    p.out = (float*)d_out;
    p.xb   = hb;
    p.a1b  = hb + 655360;
    p.nxtb = hb + 1310720;
    p.a3b  = hb + 2260992;
    p.w1b  = hb + 2686976;
    p.w2b  = hb + 2789376;
    p.w3b  = hb + 2891776;
    p.w4b  = hb + 3307520;

    void* args[] = { &p };
    hipLaunchCooperativeKernel(reinterpret_cast<void*>(fused_kernel),
                               dim3(256), dim3(256), args, 0, stream);
}